// Round 6
// baseline (491.269 us; speedup 1.0000x reference)
//
#include <hip/hip_runtime.h>

#define THREADS 256
#define NBG 128          // nodes per block in GEMM kernels (2 tiles of 16/wave)
#define HS 72            // hsb stride in bf16 units (144 B, 16B-aligned)
#define XT 132           // xsT stride in f32 units (128 nodes + 4 pad)

#define CHUNK 4096       // edges per k_bin block
#define MAXB 1024        // max buckets (N <= 131072, 128 nodes/bucket)
#define CAP 5120         // slab capacity per bucket (mean 4096 + 16 sigma)

typedef short bf16x8 __attribute__((ext_vector_type(8)));
typedef float f32x4  __attribute__((ext_vector_type(4)));

__device__ __forceinline__ float relu_f(float v) { return v > 0.f ? v : 0.f; }

__device__ __forceinline__ unsigned short f2b(float f) {   // fp32->bf16, RNE
  union { float f; unsigned u; } v; v.f = f;
  unsigned u = v.u + 0x7fffu + ((v.u >> 16) & 1u);
  return (unsigned short)(u >> 16);
}
__device__ __forceinline__ float blo(unsigned u) {
  union { unsigned x; float f; } v; v.x = u << 16; return v.f;
}
__device__ __forceinline__ float bhi(unsigned u) {
  union { unsigned x; float f; } v; v.x = u & 0xffff0000u; return v.f;
}
__device__ __forceinline__ void accq(float* a, uint4 q) {
  a[0] += blo(q.x); a[1] += bhi(q.x);
  a[2] += blo(q.y); a[3] += bhi(q.y);
  a[4] += blo(q.z); a[5] += bhi(q.z);
  a[6] += blo(q.w); a[7] += bhi(q.w);
}

// ---------------------------------------------------------------------------
// Transpose+convert: src fp32 [64][1024] -> dst bf16 [1024][64].  grid=16.
// ---------------------------------------------------------------------------
__global__ __launch_bounds__(THREADS) void k_cvtT(
    const float* __restrict__ src, unsigned short* __restrict__ dst) {
  __shared__ unsigned short ts[64 * 65];
  const int c0 = blockIdx.x * 64;
  const int t = threadIdx.x;
#pragma unroll
  for (int i = 0; i < 16; ++i) {
    int f = t + THREADS * i;
    int r = f >> 6, c = f & 63;
    ts[c * 65 + r] = f2b(src[r * 1024 + c0 + c]);
  }
  __syncthreads();
#pragma unroll
  for (int i = 0; i < 16; ++i) {
    int f = t + THREADS * i;
    int cc = f >> 6, r = f & 63;
    dst[(c0 + cc) * 64 + r] = ts[cc * 65 + r];
  }
}

__global__ __launch_bounds__(THREADS) void k_cvtC(
    const float* __restrict__ src, unsigned short* __restrict__ dst, int n) {
  int i = blockIdx.x * THREADS + threadIdx.x;
  if (i < n) dst[i] = f2b(src[i]);
}

// ---------------------------------------------------------------------------
// MFMA kernel A: ky_bf[n] = bf16( block_matmul(x[n], MLP1(ea[n])) )
// 128 nodes/block; wave w owns node-tiles w*32+{0..15, 16..31}.
// Per ct: 1 B-load pair feeds 4 MFMAs (2 tiles) -> 2x arithmetic per load.
// ---------------------------------------------------------------------------
__global__ __launch_bounds__(THREADS) void k_kyv(
    const float* __restrict__ x, const float* __restrict__ ea,
    const float* __restrict__ W1, const float* __restrict__ b1,
    const unsigned short* __restrict__ W2T, const float* __restrict__ b2,
    unsigned short* __restrict__ kyb, int N) {
  __shared__ __align__(16) unsigned short hsb[NBG * HS];
  __shared__ __align__(16) float xsT[64 * XT];
  const int t = threadIdx.x;
  const int nb0 = blockIdx.x * NBG;

  for (int i = 0; i < 32; ++i) {
    int f = t + THREADS * i;          // 128 nodes x 64 feats
    int node = f >> 6, m = f & 63;
    int gn = nb0 + node;
    float h = 0.f, xv = 0.f;
    if (gn < N) {
      float e0 = ea[gn * 3 + 0], e1 = ea[gn * 3 + 1], e2 = ea[gn * 3 + 2];
      h = relu_f(b1[m] + e0 * W1[m] + e1 * W1[64 + m] + e2 * W1[128 + m]);
      xv = x[gn * 64 + m];
    }
    hsb[node * HS + m] = f2b(h);
    xsT[m * XT + node] = xv;
  }
  __syncthreads();

  const int w = t >> 6, lane = t & 63;
  const int quad = lane >> 4, l15 = lane & 15;
  const int r0 = w * 32;

  const bf16x8 a00 = *(const bf16x8*)&hsb[(r0 + l15) * HS + quad * 8];
  const bf16x8 a01 = *(const bf16x8*)&hsb[(r0 + l15) * HS + 32 + quad * 8];
  const bf16x8 a10 = *(const bf16x8*)&hsb[(r0 + 16 + l15) * HS + quad * 8];
  const bf16x8 a11 = *(const bf16x8*)&hsb[(r0 + 16 + l15) * HS + 32 + quad * 8];

  float kyacc[2][4][4];
#pragma unroll
  for (int ti = 0; ti < 2; ++ti)
#pragma unroll
    for (int r = 0; r < 4; ++r)
#pragma unroll
      for (int c = 0; c < 4; ++c) kyacc[ti][r][c] = 0.f;

#pragma unroll 4
  for (int ct = 0; ct < 64; ++ct) {
    const unsigned short* bp = &W2T[(ct * 16 + l15) * 64 + quad * 8];
    bf16x8 bf0 = *(const bf16x8*)bp;
    bf16x8 bf1 = *(const bf16x8*)(bp + 32);
    f32x4 acc0 = {0.f, 0.f, 0.f, 0.f};
    f32x4 acc1 = {0.f, 0.f, 0.f, 0.f};
    acc0 = __builtin_amdgcn_mfma_f32_16x16x32_bf16(a00, bf0, acc0, 0, 0, 0);
    acc0 = __builtin_amdgcn_mfma_f32_16x16x32_bf16(a01, bf1, acc0, 0, 0, 0);
    acc1 = __builtin_amdgcn_mfma_f32_16x16x32_bf16(a10, bf0, acc1, 0, 0, 0);
    acc1 = __builtin_amdgcn_mfma_f32_16x16x32_bf16(a11, bf1, acc1, 0, 0, 0);
    float bb = b2[ct * 16 + l15];
    int c = ct >> 4;
    float4 xv0 = *(const float4*)&xsT[ct * XT + r0 + quad * 4];
    float4 xv1 = *(const float4*)&xsT[ct * XT + r0 + 16 + quad * 4];
    kyacc[0][0][c] += xv0.x * (acc0[0] + bb);
    kyacc[0][1][c] += xv0.y * (acc0[1] + bb);
    kyacc[0][2][c] += xv0.z * (acc0[2] + bb);
    kyacc[0][3][c] += xv0.w * (acc0[3] + bb);
    kyacc[1][0][c] += xv1.x * (acc1[0] + bb);
    kyacc[1][1][c] += xv1.y * (acc1[1] + bb);
    kyacc[1][2][c] += xv1.z * (acc1[2] + bb);
    kyacc[1][3][c] += xv1.w * (acc1[3] + bb);
  }

#pragma unroll
  for (int ti = 0; ti < 2; ++ti)
#pragma unroll
    for (int r = 0; r < 4; ++r) {
      int gn = nb0 + r0 + ti * 16 + quad * 4 + r;
      if (gn < N) {
#pragma unroll
        for (int c = 0; c < 4; ++c)
          kyb[(size_t)gn * 64 + c * 16 + l15] = f2b(kyacc[ti][r][c]);
      }
    }
}

// ---------------------------------------------------------------------------
// Pass 1: bin edges by dst>>7 into fixed-capacity bucket slabs (128 nodes ea).
// Packed entry: (ldst<<17) | src, ldst = dst & 127.
// ---------------------------------------------------------------------------
__global__ __launch_bounds__(THREADS) void k_bin(
    const int* __restrict__ ei, unsigned* __restrict__ slab,
    int* __restrict__ bcnt, int E, int N) {
  __shared__ unsigned staged[CHUNK];
  __shared__ unsigned short sb[CHUNK];
  __shared__ int lcnt[MAXB], lofs[MAXB], lcur[MAXB], gof[MAXB];
  const int nbkt = (N + 127) >> 7;
  const int t = threadIdx.x;
  const int e0 = blockIdx.x * CHUNK;
  const int cnt = min(CHUNK, E - e0);

  for (int i = t; i < nbkt; i += THREADS) lcnt[i] = 0;
  __syncthreads();
  for (int i = t; i < cnt; i += THREADS)
    atomicAdd(&lcnt[((unsigned)ei[e0 + i]) >> 7], 1);
  __syncthreads();

  const int lane = t & 63;
  if (t < 64) {
    int base = 0;
    for (int c = 0; c * 64 < nbkt; ++c) {
      int idx = c * 64 + lane;
      int v = (idx < nbkt) ? lcnt[idx] : 0;
      int inc = v;
#pragma unroll
      for (int o = 1; o < 64; o <<= 1) {
        int u = __shfl_up(inc, o);
        if (lane >= o) inc += u;
      }
      if (idx < nbkt) { lofs[idx] = base + inc - v; lcur[idx] = base + inc - v; }
      base += __shfl(inc, 63);
    }
  }
  __syncthreads();

  for (int b = t; b < nbkt; b += THREADS) {
    int need = lcnt[b];
    gof[b] = need ? atomicAdd(&bcnt[b], need) : 0;
  }
  __syncthreads();

  for (int i = t; i < cnt; i += THREADS) {
    unsigned dst = (unsigned)ei[e0 + i];
    unsigned src = (unsigned)ei[E + e0 + i];
    int b = dst >> 7;
    int p = atomicAdd(&lcur[b], 1);
    staged[p] = ((dst & 127u) << 17) | src;
    sb[p] = (unsigned short)b;
  }
  __syncthreads();

  for (int i = t; i < cnt; i += THREADS) {
    int b = sb[i];
    int dl = gof[b] + (i - lofs[b]);
    if (dl < CAP) slab[(size_t)b * CAP + dl] = staged[i];
  }
}

// ---------------------------------------------------------------------------
// Pass 2 (fused sort + gather): per-bucket LDS counting sort by ldst, then
// gather means straight from the sorted LDS run. No slab writeback, no
// beg/deg arrays. Pairwise node processing: 4 predicated 16B loads in flight.
// vconv (fp32) = d_out scratch.
// ---------------------------------------------------------------------------
__global__ __launch_bounds__(THREADS) void k_csrg(
    const unsigned* __restrict__ slab, const int* __restrict__ bcnt,
    const unsigned short* __restrict__ kyb, float* __restrict__ vconv, int N) {
  __shared__ unsigned ins[CAP];
  __shared__ unsigned outs[CAP];
  __shared__ int hist[256], excl[256], cur[256];
  __shared__ int wsum[4];
  const int b = blockIdx.x, t = threadIdx.x;
  const int nb0 = b * 128;
  int cnt = bcnt[b];
  if (cnt > CAP) cnt = CAP;
  const size_t sbase = (size_t)b * CAP;

  for (int i = t; i < cnt; i += THREADS) ins[i] = slab[sbase + i];
  hist[t] = 0;
  __syncthreads();
  for (int i = t; i < cnt; i += THREADS) atomicAdd(&hist[ins[i] >> 17], 1);
  __syncthreads();

  const int lane = t & 63, wid = t >> 6;
  int v = hist[t], inc = v;
#pragma unroll
  for (int o = 1; o < 64; o <<= 1) {
    int u = __shfl_up(inc, o);
    if (lane >= o) inc += u;
  }
  if (lane == 63) wsum[wid] = inc;
  __syncthreads();
  int add = 0;
  for (int i = 0; i < wid; ++i) add += wsum[i];
  excl[t] = add + inc - v;
  cur[t] = excl[t];
  __syncthreads();

  for (int i = t; i < cnt; i += THREADS) {
    unsigned val = ins[i];
    int p = atomicAdd(&cur[val >> 17], 1);
    outs[p] = val;
  }
  __syncthreads();

  // gather from sorted LDS run; wave w owns nodes w*32..w*32+31, in pairs
  const int w = t >> 6;
  const int es = lane >> 3, fo = lane & 7;   // 8 edge slots x 8 feature-octs

  for (int pp = 0; pp < 16; ++pp) {
    const int li0 = w * 32 + pp * 2, li1 = li0 + 1;
    const int dg0 = hist[li0], of0 = excl[li0];
    const int dg1 = hist[li1], of1 = excl[li1];
    float acc0[8], acc1[8];
#pragma unroll
    for (int i = 0; i < 8; ++i) { acc0[i] = 0.f; acc1[i] = 0.f; }

    const int mx = max(dg0, dg1);
    for (int j = 0; j < mx; j += 16) {
      int iA = j + es, iB = j + 8 + es;
      if (iA < dg0) {
        unsigned s = outs[of0 + iA] & 0x1FFFFu;
        accq(acc0, ((const uint4*)(kyb + (size_t)s * 64))[fo]);
      }
      if (iB < dg0) {
        unsigned s = outs[of0 + iB] & 0x1FFFFu;
        accq(acc0, ((const uint4*)(kyb + (size_t)s * 64))[fo]);
      }
      if (iA < dg1) {
        unsigned s = outs[of1 + iA] & 0x1FFFFu;
        accq(acc1, ((const uint4*)(kyb + (size_t)s * 64))[fo]);
      }
      if (iB < dg1) {
        unsigned s = outs[of1 + iB] & 0x1FFFFu;
        accq(acc1, ((const uint4*)(kyb + (size_t)s * 64))[fo]);
      }
    }

    float o0 = 0.f, o1 = 0.f;
#pragma unroll
    for (int i = 0; i < 8; ++i) {
      float v0 = acc0[i];
      v0 += __shfl_xor(v0, 8); v0 += __shfl_xor(v0, 16); v0 += __shfl_xor(v0, 32);
      float v1 = acc1[i];
      v1 += __shfl_xor(v1, 8); v1 += __shfl_xor(v1, 16); v1 += __shfl_xor(v1, 32);
      if (es == i) { o0 = v0; o1 = v1; }
    }
    int gn0 = nb0 + li0, gn1 = nb0 + li1;
    float c0 = dg0 > 1 ? (float)dg0 : 1.f;
    float c1 = dg1 > 1 ? (float)dg1 : 1.f;
    if (gn0 < N) vconv[(size_t)gn0 * 64 + fo * 8 + es] = o0 / c0;
    if (gn1 < N) vconv[(size_t)gn1 * 64 + fo * 8 + es] = o1 / c1;
  }
}

// ---------------------------------------------------------------------------
// MFMA kernel D: v = block_matmul(vconv, MLP2(ea)); out = v @ mixW^T + mixb
// Same 128-node 2-tile structure. vconv aliases out (own rows only).
// ---------------------------------------------------------------------------
__global__ __launch_bounds__(THREADS) void k_out(
    const float* vconv, const float* __restrict__ ea,
    const float* __restrict__ W1, const float* __restrict__ b1,
    const unsigned short* __restrict__ W2T, const float* __restrict__ b2,
    const unsigned short* __restrict__ mixWb, const float* __restrict__ mixb,
    float* out, int N) {
  __shared__ __align__(16) unsigned short hsb[NBG * HS];
  __shared__ __align__(16) float xsT[64 * XT];
  const int t = threadIdx.x;
  const int nb0 = blockIdx.x * NBG;

  for (int i = 0; i < 32; ++i) {
    int f = t + THREADS * i;
    int node = f >> 6, m = f & 63;
    int gn = nb0 + node;
    float h = 0.f, xv = 0.f;
    if (gn < N) {
      float e0 = ea[gn * 3 + 0], e1 = ea[gn * 3 + 1], e2 = ea[gn * 3 + 2];
      h = relu_f(b1[m] + e0 * W1[m] + e1 * W1[64 + m] + e2 * W1[128 + m]);
      xv = vconv[(size_t)gn * 64 + m];
    }
    hsb[node * HS + m] = f2b(h);
    xsT[m * XT + node] = xv;
  }
  __syncthreads();

  const int w = t >> 6, lane = t & 63;
  const int quad = lane >> 4, l15 = lane & 15;
  const int r0 = w * 32;

  const bf16x8 a00 = *(const bf16x8*)&hsb[(r0 + l15) * HS + quad * 8];
  const bf16x8 a01 = *(const bf16x8*)&hsb[(r0 + l15) * HS + 32 + quad * 8];
  const bf16x8 a10 = *(const bf16x8*)&hsb[(r0 + 16 + l15) * HS + quad * 8];
  const bf16x8 a11 = *(const bf16x8*)&hsb[(r0 + 16 + l15) * HS + 32 + quad * 8];

  float kyacc[2][4][4];
#pragma unroll
  for (int ti = 0; ti < 2; ++ti)
#pragma unroll
    for (int r = 0; r < 4; ++r)
#pragma unroll
      for (int c = 0; c < 4; ++c) kyacc[ti][r][c] = 0.f;

#pragma unroll 4
  for (int ct = 0; ct < 64; ++ct) {
    const unsigned short* bp = &W2T[(ct * 16 + l15) * 64 + quad * 8];
    bf16x8 bf0 = *(const bf16x8*)bp;
    bf16x8 bf1 = *(const bf16x8*)(bp + 32);
    f32x4 acc0 = {0.f, 0.f, 0.f, 0.f};
    f32x4 acc1 = {0.f, 0.f, 0.f, 0.f};
    acc0 = __builtin_amdgcn_mfma_f32_16x16x32_bf16(a00, bf0, acc0, 0, 0, 0);
    acc0 = __builtin_amdgcn_mfma_f32_16x16x32_bf16(a01, bf1, acc0, 0, 0, 0);
    acc1 = __builtin_amdgcn_mfma_f32_16x16x32_bf16(a10, bf0, acc1, 0, 0, 0);
    acc1 = __builtin_amdgcn_mfma_f32_16x16x32_bf16(a11, bf1, acc1, 0, 0, 0);
    float bb = b2[ct * 16 + l15];
    int c = ct >> 4;
    float4 xv0 = *(const float4*)&xsT[ct * XT + r0 + quad * 4];
    float4 xv1 = *(const float4*)&xsT[ct * XT + r0 + 16 + quad * 4];
    kyacc[0][0][c] += xv0.x * (acc0[0] + bb);
    kyacc[0][1][c] += xv0.y * (acc0[1] + bb);
    kyacc[0][2][c] += xv0.z * (acc0[2] + bb);
    kyacc[0][3][c] += xv0.w * (acc0[3] + bb);
    kyacc[1][0][c] += xv1.x * (acc1[0] + bb);
    kyacc[1][1][c] += xv1.y * (acc1[1] + bb);
    kyacc[1][2][c] += xv1.z * (acc1[2] + bb);
    kyacc[1][3][c] += xv1.w * (acc1[3] + bb);
  }

  // relayout v (bf16) into hsb for mix A-fragments
  __syncthreads();
#pragma unroll
  for (int ti = 0; ti < 2; ++ti)
#pragma unroll
    for (int r = 0; r < 4; ++r)
#pragma unroll
      for (int c = 0; c < 4; ++c)
        hsb[(r0 + ti * 16 + quad * 4 + r) * HS + c * 16 + l15] =
            f2b(kyacc[ti][r][c]);
  __syncthreads();

  const bf16x8 va00 = *(const bf16x8*)&hsb[(r0 + l15) * HS + quad * 8];
  const bf16x8 va01 = *(const bf16x8*)&hsb[(r0 + l15) * HS + 32 + quad * 8];
  const bf16x8 va10 = *(const bf16x8*)&hsb[(r0 + 16 + l15) * HS + quad * 8];
  const bf16x8 va11 = *(const bf16x8*)&hsb[(r0 + 16 + l15) * HS + 32 + quad * 8];

#pragma unroll
  for (int ot = 0; ot < 4; ++ot) {
    const unsigned short* mp = &mixWb[(ot * 16 + l15) * 64 + quad * 8];
    bf16x8 mb0 = *(const bf16x8*)mp;
    bf16x8 mb1 = *(const bf16x8*)(mp + 32);
    f32x4 oacc0 = {0.f, 0.f, 0.f, 0.f};
    f32x4 oacc1 = {0.f, 0.f, 0.f, 0.f};
    oacc0 = __builtin_amdgcn_mfma_f32_16x16x32_bf16(va00, mb0, oacc0, 0, 0, 0);
    oacc0 = __builtin_amdgcn_mfma_f32_16x16x32_bf16(va01, mb1, oacc0, 0, 0, 0);
    oacc1 = __builtin_amdgcn_mfma_f32_16x16x32_bf16(va10, mb0, oacc1, 0, 0, 0);
    oacc1 = __builtin_amdgcn_mfma_f32_16x16x32_bf16(va11, mb1, oacc1, 0, 0, 0);
    float mbv = mixb[ot * 16 + l15];
#pragma unroll
    for (int r = 0; r < 4; ++r) {
      int gn0 = nb0 + r0 + quad * 4 + r;
      int gn1 = gn0 + 16;
      if (gn0 < N) out[(size_t)gn0 * 64 + ot * 16 + l15] = oacc0[r] + mbv;
      if (gn1 < N) out[(size_t)gn1 * 64 + ot * 16 + l15] = oacc1[r] + mbv;
    }
  }
}

// ---------------------------------------------------------------------------
extern "C" void kernel_launch(void* const* d_in, const int* in_sizes, int n_in,
                              void* d_out, int out_size, void* d_ws, size_t ws_size,
                              hipStream_t stream) {
  const float* x    = (const float*)d_in[0];
  const float* ea   = (const float*)d_in[1];
  const int*   ei   = (const int*)d_in[2];
  const float* k1W1 = (const float*)d_in[3];
  const float* k1b1 = (const float*)d_in[4];
  const float* k1W2 = (const float*)d_in[5];
  const float* k1b2 = (const float*)d_in[6];
  const float* k2W1 = (const float*)d_in[7];
  const float* k2b1 = (const float*)d_in[8];
  const float* k2W2 = (const float*)d_in[9];
  const float* k2b2 = (const float*)d_in[10];
  const float* mixW = (const float*)d_in[11];
  const float* mixb = (const float*)d_in[12];
  float* out = (float*)d_out;

  const int N = in_sizes[0] / 64;
  const int E = in_sizes[2] / 2;
  const int nbkt = (N + 127) >> 7;

  // ws layout (~29.2 MB):
  //   kyb bf16 [N*64] | slab u32 [nbkt*CAP] | bcnt [nbkt] |
  //   W2T1b bf16 [65536] | W2T2b bf16 [65536] | mixWb bf16 [4096]
  // vconv (fp32, N*64) lives in d_out (k_out reads own rows before writing).
  unsigned short* kyb = (unsigned short*)d_ws;
  unsigned* slab = (unsigned*)(kyb + (size_t)N * 64);
  int* bcnt = (int*)(slab + (size_t)nbkt * CAP);
  unsigned short* W2T1b = (unsigned short*)(bcnt + nbkt);
  unsigned short* W2T2b = W2T1b + 65536;
  unsigned short* mixWb = W2T2b + 65536;
  float* vconv = out;

  const int gblocks = (N + NBG - 1) / NBG;
  const int bblocks = (E + CHUNK - 1) / CHUNK;

  hipMemsetAsync(bcnt, 0, (size_t)nbkt * sizeof(int), stream);

  // Weight conversions up-front (separate buffers, no hazards)
  k_cvtT<<<dim3(16), dim3(THREADS), 0, stream>>>(k1W2, W2T1b);
  k_cvtT<<<dim3(16), dim3(THREADS), 0, stream>>>(k2W2, W2T2b);
  k_cvtC<<<dim3(16), dim3(THREADS), 0, stream>>>(mixW, mixWb, 4096);

  // Phase 1: MLP1 GEMM -> ky bf16
  k_kyv<<<dim3(gblocks), dim3(THREADS), 0, stream>>>(
      x, ea, k1W1, k1b1, W2T1b, k1b2, kyb, N);

  // Phase 2: bin by bucket (128 nodes each)
  k_bin<<<dim3(bblocks), dim3(THREADS), 0, stream>>>(ei, slab, bcnt, E, N);

  // Phase 3: fused per-bucket counting sort + gather -> vconv (d_out)
  k_csrg<<<dim3(nbkt), dim3(THREADS), 0, stream>>>(slab, bcnt, kyb, vconv, N);

  // Phase 4: MLP2 GEMM + mix
  k_out<<<dim3(gblocks), dim3(THREADS), 0, stream>>>(
      vconv, ea, k2W1, k2b1, W2T2b, k2b2, mixWb, mixb, out, N);
}

// Round 7
// 324.154 us; speedup vs baseline: 1.5155x; 1.5155x over previous
//
#include <hip/hip_runtime.h>

#define THREADS 256
#define NBG 128          // nodes per block in GEMM kernels
#define HS 72            // hsb stride in bf16 units (144 B, 16B-aligned)
#define XT 132           // xsT stride in f32 units (528 B, 16B-aligned)

#define CHUNK 4096       // edges per k_bin block
#define MAXB 1024        // max buckets (N <= 131072, 128 nodes/bucket)
#define CAP 5120         // slab capacity per bucket (mean 4096 + 16 sigma)
#define GCAP 4096        // gather LDS run capacity (64 nodes, mean 2048)

typedef short bf16x8 __attribute__((ext_vector_type(8)));
typedef float f32x4  __attribute__((ext_vector_type(4)));

__device__ __forceinline__ float relu_f(float v) { return v > 0.f ? v : 0.f; }

__device__ __forceinline__ unsigned short f2b(float f) {   // fp32->bf16, RNE
  union { float f; unsigned u; } v; v.f = f;
  unsigned u = v.u + 0x7fffu + ((v.u >> 16) & 1u);
  return (unsigned short)(u >> 16);
}
__device__ __forceinline__ float blo(unsigned u) {
  union { unsigned x; float f; } v; v.x = u << 16; return v.f;
}
__device__ __forceinline__ float bhi(unsigned u) {
  union { unsigned x; float f; } v; v.x = u & 0xffff0000u; return v.f;
}
__device__ __forceinline__ void accq(float* a, uint4 q) {
  a[0] += blo(q.x); a[1] += bhi(q.x);
  a[2] += blo(q.y); a[3] += bhi(q.y);
  a[4] += blo(q.z); a[5] += bhi(q.z);
  a[6] += blo(q.w); a[7] += bhi(q.w);
}

// ---------------------------------------------------------------------------
// Transpose+convert: src fp32 [64][1024] -> dst bf16 [1024][64].  grid=16.
// ---------------------------------------------------------------------------
__global__ __launch_bounds__(THREADS) void k_cvtT(
    const float* __restrict__ src, unsigned short* __restrict__ dst) {
  __shared__ unsigned short ts[64 * 65];
  const int c0 = blockIdx.x * 64;
  const int t = threadIdx.x;
#pragma unroll
  for (int i = 0; i < 16; ++i) {
    int f = t + THREADS * i;
    int r = f >> 6, c = f & 63;
    ts[c * 65 + r] = f2b(src[r * 1024 + c0 + c]);
  }
  __syncthreads();
#pragma unroll
  for (int i = 0; i < 16; ++i) {
    int f = t + THREADS * i;
    int cc = f >> 6, r = f & 63;
    dst[(c0 + cc) * 64 + r] = ts[cc * 65 + r];
  }
}

__global__ __launch_bounds__(THREADS) void k_cvtC(
    const float* __restrict__ src, unsigned short* __restrict__ dst, int n) {
  int i = blockIdx.x * THREADS + threadIdx.x;
  if (i < n) dst[i] = f2b(src[i]);
}

// ---------------------------------------------------------------------------
// MFMA kernel A (channel-per-wave): wave w owns channel w = cts 16w..16w+15
// with the COMPLETE k-sum; 8 node-tile A-frags held in registers.
// Per ct: 2 B-loads feed 16 MFMAs. Bias folded into MFMA C-init.
// ---------------------------------------------------------------------------
__global__ __launch_bounds__(THREADS) void k_kyv(
    const float* __restrict__ x, const float* __restrict__ ea,
    const float* __restrict__ W1, const float* __restrict__ b1,
    const unsigned short* __restrict__ W2T, const float* __restrict__ b2,
    unsigned short* __restrict__ kyb, int N) {
  __shared__ __align__(16) unsigned short hsb[NBG * HS];
  __shared__ __align__(16) float xsT[64 * XT];
  const int t = threadIdx.x;
  const int nb0 = blockIdx.x * NBG;

  for (int i = 0; i < 32; ++i) {
    int f = t + THREADS * i;          // 128 nodes x 64 feats
    int node = f >> 6, m = f & 63;
    int gn = nb0 + node;
    float h = 0.f, xv = 0.f;
    if (gn < N) {
      float e0 = ea[gn * 3 + 0], e1 = ea[gn * 3 + 1], e2 = ea[gn * 3 + 2];
      h = relu_f(b1[m] + e0 * W1[m] + e1 * W1[64 + m] + e2 * W1[128 + m]);
      xv = x[gn * 64 + m];
    }
    hsb[node * HS + m] = f2b(h);
    xsT[m * XT + node] = xv;
  }
  __syncthreads();

  const int w = t >> 6, lane = t & 63;
  const int quad = lane >> 4, l15 = lane & 15;

  float bbv[16];
#pragma unroll
  for (int kk = 0; kk < 16; ++kk) bbv[kk] = b2[(w * 16 + kk) * 16 + l15];

  bf16x8 a[8][2];
#pragma unroll
  for (int ti = 0; ti < 8; ++ti) {
    a[ti][0] = *(const bf16x8*)&hsb[(ti * 16 + l15) * HS + quad * 8];
    a[ti][1] = *(const bf16x8*)&hsb[(ti * 16 + l15) * HS + 32 + quad * 8];
  }

  float kyacc[8][4];
#pragma unroll
  for (int ti = 0; ti < 8; ++ti)
#pragma unroll
    for (int r = 0; r < 4; ++r) kyacc[ti][r] = 0.f;

#pragma unroll 2
  for (int kk = 0; kk < 16; ++kk) {
    const int ct = w * 16 + kk;
    const unsigned short* bp = &W2T[(ct * 16 + l15) * 64 + quad * 8];
    bf16x8 bf0 = *(const bf16x8*)bp;
    bf16x8 bf1 = *(const bf16x8*)(bp + 32);
    const float bb = bbv[kk];
#pragma unroll
    for (int ti = 0; ti < 8; ++ti) {
      f32x4 acc = {bb, bb, bb, bb};   // bias as C-init: MFMA gives T + bb
      acc = __builtin_amdgcn_mfma_f32_16x16x32_bf16(a[ti][0], bf0, acc, 0, 0, 0);
      acc = __builtin_amdgcn_mfma_f32_16x16x32_bf16(a[ti][1], bf1, acc, 0, 0, 0);
      float4 xv = *(const float4*)&xsT[ct * XT + ti * 16 + quad * 4];
      kyacc[ti][0] += xv.x * acc[0];
      kyacc[ti][1] += xv.y * acc[1];
      kyacc[ti][2] += xv.z * acc[2];
      kyacc[ti][3] += xv.w * acc[3];
    }
  }

#pragma unroll
  for (int ti = 0; ti < 8; ++ti)
#pragma unroll
    for (int r = 0; r < 4; ++r) {
      int gn = nb0 + ti * 16 + quad * 4 + r;
      if (gn < N) kyb[(size_t)gn * 64 + w * 16 + l15] = f2b(kyacc[ti][r]);
    }
}

// ---------------------------------------------------------------------------
// Pass 1: bin edges by dst>>7 into fixed-capacity bucket slabs (128 nodes ea).
// Packed entry: (ldst<<17) | src, ldst = dst & 127.
// ---------------------------------------------------------------------------
__global__ __launch_bounds__(THREADS) void k_bin(
    const int* __restrict__ ei, unsigned* __restrict__ slab,
    int* __restrict__ bcnt, int E, int N) {
  __shared__ unsigned staged[CHUNK];
  __shared__ unsigned short sb[CHUNK];
  __shared__ int lcnt[MAXB], lofs[MAXB], lcur[MAXB], gof[MAXB];
  const int nbkt = (N + 127) >> 7;
  const int t = threadIdx.x;
  const int e0 = blockIdx.x * CHUNK;
  const int cnt = min(CHUNK, E - e0);

  for (int i = t; i < nbkt; i += THREADS) lcnt[i] = 0;
  __syncthreads();
  for (int i = t; i < cnt; i += THREADS)
    atomicAdd(&lcnt[((unsigned)ei[e0 + i]) >> 7], 1);
  __syncthreads();

  const int lane = t & 63;
  if (t < 64) {
    int base = 0;
    for (int c = 0; c * 64 < nbkt; ++c) {
      int idx = c * 64 + lane;
      int v = (idx < nbkt) ? lcnt[idx] : 0;
      int inc = v;
#pragma unroll
      for (int o = 1; o < 64; o <<= 1) {
        int u = __shfl_up(inc, o);
        if (lane >= o) inc += u;
      }
      if (idx < nbkt) { lofs[idx] = base + inc - v; lcur[idx] = base + inc - v; }
      base += __shfl(inc, 63);
    }
  }
  __syncthreads();

  for (int b = t; b < nbkt; b += THREADS) {
    int need = lcnt[b];
    gof[b] = need ? atomicAdd(&bcnt[b], need) : 0;
  }
  __syncthreads();

  for (int i = t; i < cnt; i += THREADS) {
    unsigned dst = (unsigned)ei[e0 + i];
    unsigned src = (unsigned)ei[E + e0 + i];
    int b = dst >> 7;
    int p = atomicAdd(&lcur[b], 1);
    staged[p] = ((dst & 127u) << 17) | src;
    sb[p] = (unsigned short)b;
  }
  __syncthreads();

  for (int i = t; i < cnt; i += THREADS) {
    int b = sb[i];
    int dl = gof[b] + (i - lofs[b]);
    if (dl < CAP) slab[(size_t)b * CAP + dl] = staged[i];
  }
}

// ---------------------------------------------------------------------------
// Pass 2: per-bucket LDS counting sort by ldst; write back sorted run
// (coalesced); emit beg[n]/deg[n].  128 nodes/bucket -> 42 KB LDS, 3/CU.
// ---------------------------------------------------------------------------
__global__ __launch_bounds__(THREADS) void k_csr(
    unsigned* __restrict__ slab, const int* __restrict__ bcnt,
    int* __restrict__ beg, int* __restrict__ deg, int N) {
  __shared__ unsigned ins[CAP];
  __shared__ unsigned outs[CAP];
  __shared__ int hist[128], excl[128], cur[128];
  __shared__ int wsum[2];
  const int b = blockIdx.x, t = threadIdx.x;
  int cnt = bcnt[b];
  if (cnt > CAP) cnt = CAP;
  const size_t sbase = (size_t)b * CAP;

  for (int i = t; i < cnt; i += THREADS) ins[i] = slab[sbase + i];
  if (t < 128) hist[t] = 0;
  __syncthreads();
  for (int i = t; i < cnt; i += THREADS) atomicAdd(&hist[ins[i] >> 17], 1);
  __syncthreads();

  const int lane = t & 63, wid = t >> 6;
  int v = (t < 128) ? hist[t] : 0;
  int inc = v;
#pragma unroll
  for (int o = 1; o < 64; o <<= 1) {
    int u = __shfl_up(inc, o);
    if (lane >= o) inc += u;
  }
  if (t < 128 && lane == 63) wsum[wid] = inc;
  __syncthreads();
  if (t < 128) {
    int add = (wid == 1) ? wsum[0] : 0;
    excl[t] = add + inc - v;
    cur[t] = add + inc - v;
  }
  __syncthreads();

  for (int i = t; i < cnt; i += THREADS) {
    unsigned val = ins[i];
    int p = atomicAdd(&cur[val >> 17], 1);
    outs[p] = val;
  }
  __syncthreads();
  for (int i = t; i < cnt; i += THREADS) slab[sbase + i] = outs[i];

  int n = b * 128 + t;
  if (t < 128 && n < N) {
    beg[n] = (int)sbase + excl[t];
    deg[n] = hist[t];
  }
}

// ---------------------------------------------------------------------------
// Gather: block = 64 nodes (one contiguous sorted run). Stage run in LDS
// (16 KB -> 8 blocks/CU), pairwise node processing: 4 predicated 16B kyb
// loads in flight. vconv (fp32) = d_out scratch.
// ---------------------------------------------------------------------------
__global__ __launch_bounds__(THREADS) void k_gather(
    const unsigned* __restrict__ slab, const int* __restrict__ beg,
    const int* __restrict__ deg, const unsigned short* __restrict__ kyb,
    float* __restrict__ vconv, int N) {
  __shared__ unsigned els[GCAP];
  __shared__ int sdeg[64], sofs[64];
  const int t = threadIdx.x;
  const int nb0 = blockIdx.x * 64;
  const int base = beg[nb0];

  if (t < 64) {
    int gn = nb0 + t;
    int valid = (gn < N);
    sdeg[t] = valid ? deg[gn] : 0;
    sofs[t] = valid ? (beg[gn] - base) : 0;
  }
  __syncthreads();
  const int tl = min(63, N - 1 - nb0);
  const int len = sofs[tl] + sdeg[tl];
  for (int i = t; i < len && i < GCAP; i += THREADS) els[i] = slab[base + i];
  __syncthreads();

  const int w = t >> 6, lane = t & 63;
  const int es = lane >> 3, fo = lane & 7;   // 8 edge slots x 8 feature-octs
  const bool fast = (len <= GCAP);           // block-uniform

  for (int pp = 0; pp < 8; ++pp) {
    const int li0 = w * 16 + pp * 2, li1 = li0 + 1;
    const int dg0 = sdeg[li0], of0 = sofs[li0];
    const int dg1 = sdeg[li1], of1 = sofs[li1];
    float acc0[8], acc1[8];
#pragma unroll
    for (int i = 0; i < 8; ++i) { acc0[i] = 0.f; acc1[i] = 0.f; }

    const int mx = max(dg0, dg1);
    if (fast) {
      for (int j = 0; j < mx; j += 16) {
        int iA = j + es, iB = j + 8 + es;
        if (iA < dg0) {
          unsigned s = els[of0 + iA] & 0x1FFFFu;
          accq(acc0, ((const uint4*)(kyb + (size_t)s * 64))[fo]);
        }
        if (iB < dg0) {
          unsigned s = els[of0 + iB] & 0x1FFFFu;
          accq(acc0, ((const uint4*)(kyb + (size_t)s * 64))[fo]);
        }
        if (iA < dg1) {
          unsigned s = els[of1 + iA] & 0x1FFFFu;
          accq(acc1, ((const uint4*)(kyb + (size_t)s * 64))[fo]);
        }
        if (iB < dg1) {
          unsigned s = els[of1 + iB] & 0x1FFFFu;
          accq(acc1, ((const uint4*)(kyb + (size_t)s * 64))[fo]);
        }
      }
    } else {   // overflow fallback (essentially never)
      for (int j = 0; j < mx; j += 16) {
        int iA = j + es, iB = j + 8 + es;
        if (iA < dg0) {
          unsigned s = slab[base + of0 + iA] & 0x1FFFFu;
          accq(acc0, ((const uint4*)(kyb + (size_t)s * 64))[fo]);
        }
        if (iB < dg0) {
          unsigned s = slab[base + of0 + iB] & 0x1FFFFu;
          accq(acc0, ((const uint4*)(kyb + (size_t)s * 64))[fo]);
        }
        if (iA < dg1) {
          unsigned s = slab[base + of1 + iA] & 0x1FFFFu;
          accq(acc1, ((const uint4*)(kyb + (size_t)s * 64))[fo]);
        }
        if (iB < dg1) {
          unsigned s = slab[base + of1 + iB] & 0x1FFFFu;
          accq(acc1, ((const uint4*)(kyb + (size_t)s * 64))[fo]);
        }
      }
    }

    float o0 = 0.f, o1 = 0.f;
#pragma unroll
    for (int i = 0; i < 8; ++i) {
      float v0 = acc0[i];
      v0 += __shfl_xor(v0, 8); v0 += __shfl_xor(v0, 16); v0 += __shfl_xor(v0, 32);
      float v1 = acc1[i];
      v1 += __shfl_xor(v1, 8); v1 += __shfl_xor(v1, 16); v1 += __shfl_xor(v1, 32);
      if (es == i) { o0 = v0; o1 = v1; }
    }
    int gn0 = nb0 + li0, gn1 = nb0 + li1;
    float c0 = dg0 > 1 ? (float)dg0 : 1.f;
    float c1 = dg1 > 1 ? (float)dg1 : 1.f;
    if (gn0 < N) vconv[(size_t)gn0 * 64 + fo * 8 + es] = o0 / c0;
    if (gn1 < N) vconv[(size_t)gn1 * 64 + fo * 8 + es] = o1 / c1;
  }
}

// ---------------------------------------------------------------------------
// MFMA kernel D (channel-per-wave) + mix epilogue.
// vconv aliases out (own rows only).
// ---------------------------------------------------------------------------
__global__ __launch_bounds__(THREADS) void k_out(
    const float* vconv, const float* __restrict__ ea,
    const float* __restrict__ W1, const float* __restrict__ b1,
    const unsigned short* __restrict__ W2T, const float* __restrict__ b2,
    const unsigned short* __restrict__ mixWb, const float* __restrict__ mixb,
    float* out, int N) {
  __shared__ __align__(16) unsigned short hsb[NBG * HS];
  __shared__ __align__(16) float xsT[64 * XT];
  const int t = threadIdx.x;
  const int nb0 = blockIdx.x * NBG;

  for (int i = 0; i < 32; ++i) {
    int f = t + THREADS * i;
    int node = f >> 6, m = f & 63;
    int gn = nb0 + node;
    float h = 0.f, xv = 0.f;
    if (gn < N) {
      float e0 = ea[gn * 3 + 0], e1 = ea[gn * 3 + 1], e2 = ea[gn * 3 + 2];
      h = relu_f(b1[m] + e0 * W1[m] + e1 * W1[64 + m] + e2 * W1[128 + m]);
      xv = vconv[(size_t)gn * 64 + m];
    }
    hsb[node * HS + m] = f2b(h);
    xsT[m * XT + node] = xv;
  }
  __syncthreads();

  const int w = t >> 6, lane = t & 63;
  const int quad = lane >> 4, l15 = lane & 15;

  float bbv[16];
#pragma unroll
  for (int kk = 0; kk < 16; ++kk) bbv[kk] = b2[(w * 16 + kk) * 16 + l15];

  bf16x8 a[8][2];
#pragma unroll
  for (int ti = 0; ti < 8; ++ti) {
    a[ti][0] = *(const bf16x8*)&hsb[(ti * 16 + l15) * HS + quad * 8];
    a[ti][1] = *(const bf16x8*)&hsb[(ti * 16 + l15) * HS + 32 + quad * 8];
  }

  float kyacc[8][4];
#pragma unroll
  for (int ti = 0; ti < 8; ++ti)
#pragma unroll
    for (int r = 0; r < 4; ++r) kyacc[ti][r] = 0.f;

#pragma unroll 2
  for (int kk = 0; kk < 16; ++kk) {
    const int ct = w * 16 + kk;
    const unsigned short* bp = &W2T[(ct * 16 + l15) * 64 + quad * 8];
    bf16x8 bf0 = *(const bf16x8*)bp;
    bf16x8 bf1 = *(const bf16x8*)(bp + 32);
    const float bb = bbv[kk];
#pragma unroll
    for (int ti = 0; ti < 8; ++ti) {
      f32x4 acc = {bb, bb, bb, bb};
      acc = __builtin_amdgcn_mfma_f32_16x16x32_bf16(a[ti][0], bf0, acc, 0, 0, 0);
      acc = __builtin_amdgcn_mfma_f32_16x16x32_bf16(a[ti][1], bf1, acc, 0, 0, 0);
      float4 xv = *(const float4*)&xsT[ct * XT + ti * 16 + quad * 4];
      kyacc[ti][0] += xv.x * acc[0];
      kyacc[ti][1] += xv.y * acc[1];
      kyacc[ti][2] += xv.z * acc[2];
      kyacc[ti][3] += xv.w * acc[3];
    }
  }

  // relayout v (bf16) into hsb: wave w writes its 16 columns for all 128 rows
  __syncthreads();
#pragma unroll
  for (int ti = 0; ti < 8; ++ti)
#pragma unroll
    for (int r = 0; r < 4; ++r)
      hsb[(ti * 16 + quad * 4 + r) * HS + w * 16 + l15] = f2b(kyacc[ti][r]);
  __syncthreads();

  // mix: wave w handles node-tiles 2w, 2w+1 (rows w*32 .. w*32+31)
  const int r0 = w * 32;
  const bf16x8 va00 = *(const bf16x8*)&hsb[(r0 + l15) * HS + quad * 8];
  const bf16x8 va01 = *(const bf16x8*)&hsb[(r0 + l15) * HS + 32 + quad * 8];
  const bf16x8 va10 = *(const bf16x8*)&hsb[(r0 + 16 + l15) * HS + quad * 8];
  const bf16x8 va11 = *(const bf16x8*)&hsb[(r0 + 16 + l15) * HS + 32 + quad * 8];

#pragma unroll
  for (int ot = 0; ot < 4; ++ot) {
    const unsigned short* mp = &mixWb[(ot * 16 + l15) * 64 + quad * 8];
    bf16x8 mb0 = *(const bf16x8*)mp;
    bf16x8 mb1 = *(const bf16x8*)(mp + 32);
    float mbv = mixb[ot * 16 + l15];
    f32x4 oacc0 = {mbv, mbv, mbv, mbv};
    f32x4 oacc1 = {mbv, mbv, mbv, mbv};
    oacc0 = __builtin_amdgcn_mfma_f32_16x16x32_bf16(va00, mb0, oacc0, 0, 0, 0);
    oacc0 = __builtin_amdgcn_mfma_f32_16x16x32_bf16(va01, mb1, oacc0, 0, 0, 0);
    oacc1 = __builtin_amdgcn_mfma_f32_16x16x32_bf16(va10, mb0, oacc1, 0, 0, 0);
    oacc1 = __builtin_amdgcn_mfma_f32_16x16x32_bf16(va11, mb1, oacc1, 0, 0, 0);
#pragma unroll
    for (int r = 0; r < 4; ++r) {
      int gn0 = nb0 + r0 + quad * 4 + r;
      int gn1 = gn0 + 16;
      if (gn0 < N) out[(size_t)gn0 * 64 + ot * 16 + l15] = oacc0[r];
      if (gn1 < N) out[(size_t)gn1 * 64 + ot * 16 + l15] = oacc1[r];
    }
  }
}

// ---------------------------------------------------------------------------
extern "C" void kernel_launch(void* const* d_in, const int* in_sizes, int n_in,
                              void* d_out, int out_size, void* d_ws, size_t ws_size,
                              hipStream_t stream) {
  const float* x    = (const float*)d_in[0];
  const float* ea   = (const float*)d_in[1];
  const int*   ei   = (const int*)d_in[2];
  const float* k1W1 = (const float*)d_in[3];
  const float* k1b1 = (const float*)d_in[4];
  const float* k1W2 = (const float*)d_in[5];
  const float* k1b2 = (const float*)d_in[6];
  const float* k2W1 = (const float*)d_in[7];
  const float* k2b1 = (const float*)d_in[8];
  const float* k2W2 = (const float*)d_in[9];
  const float* k2b2 = (const float*)d_in[10];
  const float* mixW = (const float*)d_in[11];
  const float* mixb = (const float*)d_in[12];
  float* out = (float*)d_out;

  const int N = in_sizes[0] / 64;
  const int E = in_sizes[2] / 2;
  const int nbkt = (N + 127) >> 7;

  // ws layout (~30 MB):
  //   kyb bf16 [N*64] | slab u32 [nbkt*CAP] | bcnt [nbkt] | beg[N] | deg[N] |
  //   W2T1b bf16 [65536] | W2T2b bf16 [65536] | mixWb bf16 [4096]
  // vconv (fp32, N*64) lives in d_out (k_out reads own rows before writing).
  unsigned short* kyb = (unsigned short*)d_ws;
  unsigned* slab = (unsigned*)(kyb + (size_t)N * 64);
  int* bcnt = (int*)(slab + (size_t)nbkt * CAP);
  int* beg  = bcnt + nbkt;
  int* deg  = beg + N;
  unsigned short* W2T1b = (unsigned short*)(deg + N);
  unsigned short* W2T2b = W2T1b + 65536;
  unsigned short* mixWb = W2T2b + 65536;
  float* vconv = out;

  const int gblocks = (N + NBG - 1) / NBG;
  const int bblocks = (E + CHUNK - 1) / CHUNK;

  hipMemsetAsync(bcnt, 0, (size_t)nbkt * sizeof(int), stream);

  k_cvtT<<<dim3(16), dim3(THREADS), 0, stream>>>(k1W2, W2T1b);
  k_cvtT<<<dim3(16), dim3(THREADS), 0, stream>>>(k2W2, W2T2b);
  k_cvtC<<<dim3(16), dim3(THREADS), 0, stream>>>(mixW, mixWb, 4096);

  // Phase 1: MLP1 GEMM -> ky bf16
  k_kyv<<<dim3(gblocks), dim3(THREADS), 0, stream>>>(
      x, ea, k1W1, k1b1, W2T1b, k1b2, kyb, N);

  // Phase 2: bin by 128-node bucket, then sort + writeback + beg/deg
  k_bin<<<dim3(bblocks), dim3(THREADS), 0, stream>>>(ei, slab, bcnt, E, N);
  k_csr<<<dim3(nbkt), dim3(THREADS), 0, stream>>>(slab, bcnt, beg, deg, N);

  // Phase 3: gather (high occupancy, pairwise ILP) -> vconv (d_out)
  k_gather<<<dim3((N + 63) / 64), dim3(THREADS), 0, stream>>>(
      slab, beg, deg, kyb, vconv, N);

  // Phase 4: MLP2 GEMM + mix
  k_out<<<dim3(gblocks), dim3(THREADS), 0, stream>>>(
      vconv, ea, k2W1, k2b1, W2T2b, k2b2, mixWb, mixb, out, N);
}

// Round 8
// 286.035 us; speedup vs baseline: 1.7175x; 1.1333x over previous
//
#include <hip/hip_runtime.h>

#define THREADS 256
#define NBG 128          // nodes per block in GEMM kernels
#define HS 72            // hsb stride in bf16 units (144 B, 16B-aligned)
#define XTB 136          // xsb node-stride in bf16 units (272 B, 8B-aligned)

#define CHUNK 4096       // edges per k_bin block
#define MAXB 1024        // max buckets (N <= 131072, 128 nodes/bucket)
#define CAP 5120         // slab capacity per bucket (mean 4096 + 16 sigma)
#define GCAP 4096        // gather LDS run capacity (64 nodes, mean 2048)

typedef short bf16x8 __attribute__((ext_vector_type(8)));
typedef short bf16x4 __attribute__((ext_vector_type(4)));
typedef float f32x4  __attribute__((ext_vector_type(4)));

__device__ __forceinline__ float relu_f(float v) { return v > 0.f ? v : 0.f; }

__device__ __forceinline__ unsigned short f2b(float f) {   // fp32->bf16, RNE
  union { float f; unsigned u; } v; v.f = f;
  unsigned u = v.u + 0x7fffu + ((v.u >> 16) & 1u);
  return (unsigned short)(u >> 16);
}
__device__ __forceinline__ float b2f(short s) {
  union { unsigned u; float f; } v;
  v.u = ((unsigned)(unsigned short)s) << 16; return v.f;
}
__device__ __forceinline__ float blo(unsigned u) {
  union { unsigned x; float f; } v; v.x = u << 16; return v.f;
}
__device__ __forceinline__ float bhi(unsigned u) {
  union { unsigned x; float f; } v; v.x = u & 0xffff0000u; return v.f;
}
__device__ __forceinline__ void accq(float* a, uint4 q) {
  a[0] += blo(q.x); a[1] += bhi(q.x);
  a[2] += blo(q.y); a[3] += bhi(q.y);
  a[4] += blo(q.z); a[5] += bhi(q.z);
  a[6] += blo(q.w); a[7] += bhi(q.w);
}

// ---------------------------------------------------------------------------
// k_prep: grid=33. Blocks 0..15: k1W2 -> W2T1b (transposed bf16);
// 16..31: k2W2 -> W2T2b; 32: mixW cvt + bcnt zero.
// ---------------------------------------------------------------------------
__global__ __launch_bounds__(THREADS) void k_prep(
    const float* __restrict__ k1W2, const float* __restrict__ k2W2,
    const float* __restrict__ mixW,
    unsigned short* __restrict__ W2T1b, unsigned short* __restrict__ W2T2b,
    unsigned short* __restrict__ mixWb, int* __restrict__ bcnt, int nbkt) {
  const int b = blockIdx.x, t = threadIdx.x;
  if (b < 32) {
    __shared__ unsigned short ts[64 * 65];
    const float* src = (b < 16) ? k1W2 : k2W2;
    unsigned short* dst = (b < 16) ? W2T1b : W2T2b;
    const int c0 = (b & 15) * 64;
#pragma unroll
    for (int i = 0; i < 16; ++i) {
      int f = t + THREADS * i;
      int r = f >> 6, c = f & 63;
      ts[c * 65 + r] = f2b(src[r * 1024 + c0 + c]);
    }
    __syncthreads();
#pragma unroll
    for (int i = 0; i < 16; ++i) {
      int f = t + THREADS * i;
      int cc = f >> 6, r = f & 63;
      dst[(c0 + cc) * 64 + r] = ts[cc * 65 + r];
    }
  } else {
#pragma unroll
    for (int i = 0; i < 16; ++i) {
      int f = t + THREADS * i;
      mixWb[f] = f2b(mixW[f]);
    }
    for (int i = t; i < nbkt; i += THREADS) bcnt[i] = 0;
  }
}

// ---------------------------------------------------------------------------
// MFMA kernel A (channel-per-wave): wave w owns channel w = cts 16w..16w+15;
// 8 node-tile A-frags in registers; per ct 2 B-loads feed 16 MFMAs.
// Prologue: ea staged in LDS, W1/b1 in regs, x via float4, xsb bf16.
// ---------------------------------------------------------------------------
__global__ __launch_bounds__(THREADS, 4) void k_kyv(
    const float* __restrict__ x, const float* __restrict__ ea,
    const float* __restrict__ W1, const float* __restrict__ b1,
    const unsigned short* __restrict__ W2T, const float* __restrict__ b2,
    unsigned short* __restrict__ kyb, int N) {
  __shared__ __align__(16) unsigned short hsb[NBG * HS];
  __shared__ __align__(16) unsigned short xsb[64 * XTB];
  __shared__ float eas[NBG * 3];
  const int t = threadIdx.x;
  const int nb0 = blockIdx.x * NBG;

  // stage edge_attr (384 floats, coalesced; zero-fill OOB)
  for (int i = t; i < NBG * 3; i += THREADS) {
    int gi = nb0 * 3 + i;
    eas[i] = (gi < N * 3) ? ea[gi] : 0.f;
  }
  __syncthreads();

  // h tile: m = t&63 invariant -> W1 row in regs
  {
    const int m = t & 63;
    const float w1a = W1[m], w1b = W1[64 + m], w1c = W1[128 + m], b1v = b1[m];
    const int n0 = t >> 6;
#pragma unroll
    for (int i = 0; i < 32; ++i) {
      int node = n0 + 4 * i;
      float h = relu_f(b1v + eas[node * 3] * w1a + eas[node * 3 + 1] * w1b +
                       eas[node * 3 + 2] * w1c);
      hsb[node * HS + m] = f2b(h);
    }
  }
  // x tile: float4 loads, bf16 transpose-store
#pragma unroll
  for (int i = 0; i < 8; ++i) {
    int f = t + THREADS * i;        // 0..2047
    int node = f >> 4, c4 = f & 15;
    int gn = nb0 + node;
    float4 xv = make_float4(0.f, 0.f, 0.f, 0.f);
    if (gn < N) xv = *(const float4*)&x[(size_t)gn * 64 + c4 * 4];
    int mb = c4 * 4;
    xsb[(mb + 0) * XTB + node] = f2b(xv.x);
    xsb[(mb + 1) * XTB + node] = f2b(xv.y);
    xsb[(mb + 2) * XTB + node] = f2b(xv.z);
    xsb[(mb + 3) * XTB + node] = f2b(xv.w);
  }
  __syncthreads();

  const int w = t >> 6, lane = t & 63;
  const int quad = lane >> 4, l15 = lane & 15;

  bf16x8 a[8][2];
#pragma unroll
  for (int ti = 0; ti < 8; ++ti) {
    a[ti][0] = *(const bf16x8*)&hsb[(ti * 16 + l15) * HS + quad * 8];
    a[ti][1] = *(const bf16x8*)&hsb[(ti * 16 + l15) * HS + 32 + quad * 8];
  }

  float kyacc[8][4];
#pragma unroll
  for (int ti = 0; ti < 8; ++ti)
#pragma unroll
    for (int r = 0; r < 4; ++r) kyacc[ti][r] = 0.f;

#pragma unroll 2
  for (int kk = 0; kk < 16; ++kk) {
    const int ct = w * 16 + kk;
    const unsigned short* bp = &W2T[(ct * 16 + l15) * 64 + quad * 8];
    bf16x8 bf0 = *(const bf16x8*)bp;
    bf16x8 bf1 = *(const bf16x8*)(bp + 32);
    const float bb = b2[ct * 16 + l15];
#pragma unroll
    for (int ti = 0; ti < 8; ++ti) {
      f32x4 acc = {bb, bb, bb, bb};   // bias folded into C-init
      acc = __builtin_amdgcn_mfma_f32_16x16x32_bf16(a[ti][0], bf0, acc, 0, 0, 0);
      acc = __builtin_amdgcn_mfma_f32_16x16x32_bf16(a[ti][1], bf1, acc, 0, 0, 0);
      bf16x4 xq = *(const bf16x4*)&xsb[ct * XTB + ti * 16 + quad * 4];
      kyacc[ti][0] += b2f(xq[0]) * acc[0];
      kyacc[ti][1] += b2f(xq[1]) * acc[1];
      kyacc[ti][2] += b2f(xq[2]) * acc[2];
      kyacc[ti][3] += b2f(xq[3]) * acc[3];
    }
  }

#pragma unroll
  for (int ti = 0; ti < 8; ++ti)
#pragma unroll
    for (int r = 0; r < 4; ++r) {
      int gn = nb0 + ti * 16 + quad * 4 + r;
      if (gn < N) kyb[(size_t)gn * 64 + w * 16 + l15] = f2b(kyacc[ti][r]);
    }
}

// ---------------------------------------------------------------------------
// Pass 1: bin edges by dst>>7 into fixed-capacity bucket slabs (128 nodes ea).
// Packed entry: (ldst<<17) | src, ldst = dst & 127.
// ---------------------------------------------------------------------------
__global__ __launch_bounds__(THREADS) void k_bin(
    const int* __restrict__ ei, unsigned* __restrict__ slab,
    int* __restrict__ bcnt, int E, int N) {
  __shared__ unsigned staged[CHUNK];
  __shared__ unsigned short sb[CHUNK];
  __shared__ int lcnt[MAXB], lofs[MAXB], lcur[MAXB], gof[MAXB];
  const int nbkt = (N + 127) >> 7;
  const int t = threadIdx.x;
  const int e0 = blockIdx.x * CHUNK;
  const int cnt = min(CHUNK, E - e0);

  for (int i = t; i < nbkt; i += THREADS) lcnt[i] = 0;
  __syncthreads();
  for (int i = t; i < cnt; i += THREADS)
    atomicAdd(&lcnt[((unsigned)ei[e0 + i]) >> 7], 1);
  __syncthreads();

  const int lane = t & 63;
  if (t < 64) {
    int base = 0;
    for (int c = 0; c * 64 < nbkt; ++c) {
      int idx = c * 64 + lane;
      int v = (idx < nbkt) ? lcnt[idx] : 0;
      int inc = v;
#pragma unroll
      for (int o = 1; o < 64; o <<= 1) {
        int u = __shfl_up(inc, o);
        if (lane >= o) inc += u;
      }
      if (idx < nbkt) { lofs[idx] = base + inc - v; lcur[idx] = base + inc - v; }
      base += __shfl(inc, 63);
    }
  }
  __syncthreads();

  for (int b = t; b < nbkt; b += THREADS) {
    int need = lcnt[b];
    gof[b] = need ? atomicAdd(&bcnt[b], need) : 0;
  }
  __syncthreads();

  for (int i = t; i < cnt; i += THREADS) {
    unsigned dst = (unsigned)ei[e0 + i];
    unsigned src = (unsigned)ei[E + e0 + i];
    int b = dst >> 7;
    int p = atomicAdd(&lcur[b], 1);
    staged[p] = ((dst & 127u) << 17) | src;
    sb[p] = (unsigned short)b;
  }
  __syncthreads();

  for (int i = t; i < cnt; i += THREADS) {
    int b = sb[i];
    int dl = gof[b] + (i - lofs[b]);
    if (dl < CAP) slab[(size_t)b * CAP + dl] = staged[i];
  }
}

// ---------------------------------------------------------------------------
// Pass 2: per-bucket LDS counting sort by ldst; write back sorted run
// (coalesced); emit beg[n]/deg[n].
// ---------------------------------------------------------------------------
__global__ __launch_bounds__(THREADS) void k_csr(
    unsigned* __restrict__ slab, const int* __restrict__ bcnt,
    int* __restrict__ beg, int* __restrict__ deg, int N) {
  __shared__ unsigned ins[CAP];
  __shared__ unsigned outs[CAP];
  __shared__ int hist[128], excl[128], cur[128];
  __shared__ int wsum[2];
  const int b = blockIdx.x, t = threadIdx.x;
  int cnt = bcnt[b];
  if (cnt > CAP) cnt = CAP;
  const size_t sbase = (size_t)b * CAP;

  for (int i = t; i < cnt; i += THREADS) ins[i] = slab[sbase + i];
  if (t < 128) hist[t] = 0;
  __syncthreads();
  for (int i = t; i < cnt; i += THREADS) atomicAdd(&hist[ins[i] >> 17], 1);
  __syncthreads();

  const int lane = t & 63, wid = t >> 6;
  int v = (t < 128) ? hist[t] : 0;
  int inc = v;
#pragma unroll
  for (int o = 1; o < 64; o <<= 1) {
    int u = __shfl_up(inc, o);
    if (lane >= o) inc += u;
  }
  if (t < 128 && lane == 63) wsum[wid] = inc;
  __syncthreads();
  if (t < 128) {
    int add = (wid == 1) ? wsum[0] : 0;
    excl[t] = add + inc - v;
    cur[t] = add + inc - v;
  }
  __syncthreads();

  for (int i = t; i < cnt; i += THREADS) {
    unsigned val = ins[i];
    int p = atomicAdd(&cur[val >> 17], 1);
    outs[p] = val;
  }
  __syncthreads();
  for (int i = t; i < cnt; i += THREADS) slab[sbase + i] = outs[i];

  int n = b * 128 + t;
  if (t < 128 && n < N) {
    beg[n] = (int)sbase + excl[t];
    deg[n] = hist[t];
  }
}

// ---------------------------------------------------------------------------
// Gather: block = 64 nodes (one contiguous sorted run). Stage run in LDS
// (16 KB -> 8 blocks/CU), pairwise nodes: 4 predicated 16B kyb loads in
// flight. vconv (fp32) = d_out scratch.
// ---------------------------------------------------------------------------
__global__ __launch_bounds__(THREADS) void k_gather(
    const unsigned* __restrict__ slab, const int* __restrict__ beg,
    const int* __restrict__ deg, const unsigned short* __restrict__ kyb,
    float* __restrict__ vconv, int N) {
  __shared__ unsigned els[GCAP];
  __shared__ int sdeg[64], sofs[64];
  const int t = threadIdx.x;
  const int nb0 = blockIdx.x * 64;
  const int base = beg[nb0];

  if (t < 64) {
    int gn = nb0 + t;
    int valid = (gn < N);
    sdeg[t] = valid ? deg[gn] : 0;
    sofs[t] = valid ? (beg[gn] - base) : 0;
  }
  __syncthreads();
  const int tl = min(63, N - 1 - nb0);
  const int len = sofs[tl] + sdeg[tl];
  for (int i = t; i < len && i < GCAP; i += THREADS) els[i] = slab[base + i];
  __syncthreads();

  const int w = t >> 6, lane = t & 63;
  const int es = lane >> 3, fo = lane & 7;   // 8 edge slots x 8 feature-octs
  const bool fast = (len <= GCAP);

  for (int pp = 0; pp < 8; ++pp) {
    const int li0 = w * 16 + pp * 2, li1 = li0 + 1;
    const int dg0 = sdeg[li0], of0 = sofs[li0];
    const int dg1 = sdeg[li1], of1 = sofs[li1];
    float acc0[8], acc1[8];
#pragma unroll
    for (int i = 0; i < 8; ++i) { acc0[i] = 0.f; acc1[i] = 0.f; }

    const int mx = max(dg0, dg1);
    if (fast) {
      for (int j = 0; j < mx; j += 16) {
        int iA = j + es, iB = j + 8 + es;
        if (iA < dg0) {
          unsigned s = els[of0 + iA] & 0x1FFFFu;
          accq(acc0, ((const uint4*)(kyb + (size_t)s * 64))[fo]);
        }
        if (iB < dg0) {
          unsigned s = els[of0 + iB] & 0x1FFFFu;
          accq(acc0, ((const uint4*)(kyb + (size_t)s * 64))[fo]);
        }
        if (iA < dg1) {
          unsigned s = els[of1 + iA] & 0x1FFFFu;
          accq(acc1, ((const uint4*)(kyb + (size_t)s * 64))[fo]);
        }
        if (iB < dg1) {
          unsigned s = els[of1 + iB] & 0x1FFFFu;
          accq(acc1, ((const uint4*)(kyb + (size_t)s * 64))[fo]);
        }
      }
    } else {   // overflow fallback (essentially never)
      for (int j = 0; j < mx; j += 16) {
        int iA = j + es, iB = j + 8 + es;
        if (iA < dg0) {
          unsigned s = slab[base + of0 + iA] & 0x1FFFFu;
          accq(acc0, ((const uint4*)(kyb + (size_t)s * 64))[fo]);
        }
        if (iB < dg0) {
          unsigned s = slab[base + of0 + iB] & 0x1FFFFu;
          accq(acc0, ((const uint4*)(kyb + (size_t)s * 64))[fo]);
        }
        if (iA < dg1) {
          unsigned s = slab[base + of1 + iA] & 0x1FFFFu;
          accq(acc1, ((const uint4*)(kyb + (size_t)s * 64))[fo]);
        }
        if (iB < dg1) {
          unsigned s = slab[base + of1 + iB] & 0x1FFFFu;
          accq(acc1, ((const uint4*)(kyb + (size_t)s * 64))[fo]);
        }
      }
    }

    float o0 = 0.f, o1 = 0.f;
#pragma unroll
    for (int i = 0; i < 8; ++i) {
      float v0 = acc0[i];
      v0 += __shfl_xor(v0, 8); v0 += __shfl_xor(v0, 16); v0 += __shfl_xor(v0, 32);
      float v1 = acc1[i];
      v1 += __shfl_xor(v1, 8); v1 += __shfl_xor(v1, 16); v1 += __shfl_xor(v1, 32);
      if (es == i) { o0 = v0; o1 = v1; }
    }
    int gn0 = nb0 + li0, gn1 = nb0 + li1;
    float c0 = dg0 > 1 ? (float)dg0 : 1.f;
    float c1 = dg1 > 1 ? (float)dg1 : 1.f;
    if (gn0 < N) vconv[(size_t)gn0 * 64 + fo * 8 + es] = o0 / c0;
    if (gn1 < N) vconv[(size_t)gn1 * 64 + fo * 8 + es] = o1 / c1;
  }
}

// ---------------------------------------------------------------------------
// MFMA kernel D (channel-per-wave) + mix epilogue. Same prologue scheme as
// k_kyv but x := vconv. vconv aliases out (own rows only).
// ---------------------------------------------------------------------------
__global__ __launch_bounds__(THREADS, 4) void k_out(
    const float* vconv, const float* __restrict__ ea,
    const float* __restrict__ W1, const float* __restrict__ b1,
    const unsigned short* __restrict__ W2T, const float* __restrict__ b2,
    const unsigned short* __restrict__ mixWb, const float* __restrict__ mixb,
    float* out, int N) {
  __shared__ __align__(16) unsigned short hsb[NBG * HS];
  __shared__ __align__(16) unsigned short xsb[64 * XTB];
  __shared__ float eas[NBG * 3];
  const int t = threadIdx.x;
  const int nb0 = blockIdx.x * NBG;

  for (int i = t; i < NBG * 3; i += THREADS) {
    int gi = nb0 * 3 + i;
    eas[i] = (gi < N * 3) ? ea[gi] : 0.f;
  }
  __syncthreads();

  {
    const int m = t & 63;
    const float w1a = W1[m], w1b = W1[64 + m], w1c = W1[128 + m], b1v = b1[m];
    const int n0 = t >> 6;
#pragma unroll
    for (int i = 0; i < 32; ++i) {
      int node = n0 + 4 * i;
      float h = relu_f(b1v + eas[node * 3] * w1a + eas[node * 3 + 1] * w1b +
                       eas[node * 3 + 2] * w1c);
      hsb[node * HS + m] = f2b(h);
    }
  }
#pragma unroll
  for (int i = 0; i < 8; ++i) {
    int f = t + THREADS * i;
    int node = f >> 4, c4 = f & 15;
    int gn = nb0 + node;
    float4 xv = make_float4(0.f, 0.f, 0.f, 0.f);
    if (gn < N) xv = *(const float4*)&vconv[(size_t)gn * 64 + c4 * 4];
    int mb = c4 * 4;
    xsb[(mb + 0) * XTB + node] = f2b(xv.x);
    xsb[(mb + 1) * XTB + node] = f2b(xv.y);
    xsb[(mb + 2) * XTB + node] = f2b(xv.z);
    xsb[(mb + 3) * XTB + node] = f2b(xv.w);
  }
  __syncthreads();

  const int w = t >> 6, lane = t & 63;
  const int quad = lane >> 4, l15 = lane & 15;

  bf16x8 a[8][2];
#pragma unroll
  for (int ti = 0; ti < 8; ++ti) {
    a[ti][0] = *(const bf16x8*)&hsb[(ti * 16 + l15) * HS + quad * 8];
    a[ti][1] = *(const bf16x8*)&hsb[(ti * 16 + l15) * HS + 32 + quad * 8];
  }

  float kyacc[8][4];
#pragma unroll
  for (int ti = 0; ti < 8; ++ti)
#pragma unroll
    for (int r = 0; r < 4; ++r) kyacc[ti][r] = 0.f;

#pragma unroll 2
  for (int kk = 0; kk < 16; ++kk) {
    const int ct = w * 16 + kk;
    const unsigned short* bp = &W2T[(ct * 16 + l15) * 64 + quad * 8];
    bf16x8 bf0 = *(const bf16x8*)bp;
    bf16x8 bf1 = *(const bf16x8*)(bp + 32);
    const float bb = b2[ct * 16 + l15];
#pragma unroll
    for (int ti = 0; ti < 8; ++ti) {
      f32x4 acc = {bb, bb, bb, bb};
      acc = __builtin_amdgcn_mfma_f32_16x16x32_bf16(a[ti][0], bf0, acc, 0, 0, 0);
      acc = __builtin_amdgcn_mfma_f32_16x16x32_bf16(a[ti][1], bf1, acc, 0, 0, 0);
      bf16x4 xq = *(const bf16x4*)&xsb[ct * XTB + ti * 16 + quad * 4];
      kyacc[ti][0] += b2f(xq[0]) * acc[0];
      kyacc[ti][1] += b2f(xq[1]) * acc[1];
      kyacc[ti][2] += b2f(xq[2]) * acc[2];
      kyacc[ti][3] += b2f(xq[3]) * acc[3];
    }
  }

  // relayout v (bf16) into hsb: wave w writes its 16 columns for all 128 rows
  __syncthreads();
#pragma unroll
  for (int ti = 0; ti < 8; ++ti)
#pragma unroll
    for (int r = 0; r < 4; ++r)
      hsb[(ti * 16 + quad * 4 + r) * HS + w * 16 + l15] = f2b(kyacc[ti][r]);
  __syncthreads();

  // mix: wave w handles node-tiles 2w, 2w+1 (rows w*32 .. w*32+31)
  const int r0 = w * 32;
  const bf16x8 va00 = *(const bf16x8*)&hsb[(r0 + l15) * HS + quad * 8];
  const bf16x8 va01 = *(const bf16x8*)&hsb[(r0 + l15) * HS + 32 + quad * 8];
  const bf16x8 va10 = *(const bf16x8*)&hsb[(r0 + 16 + l15) * HS + quad * 8];
  const bf16x8 va11 = *(const bf16x8*)&hsb[(r0 + 16 + l15) * HS + 32 + quad * 8];

#pragma unroll
  for (int ot = 0; ot < 4; ++ot) {
    const unsigned short* mp = &mixWb[(ot * 16 + l15) * 64 + quad * 8];
    bf16x8 mb0 = *(const bf16x8*)mp;
    bf16x8 mb1 = *(const bf16x8*)(mp + 32);
    float mbv = mixb[ot * 16 + l15];
    f32x4 oacc0 = {mbv, mbv, mbv, mbv};
    f32x4 oacc1 = {mbv, mbv, mbv, mbv};
    oacc0 = __builtin_amdgcn_mfma_f32_16x16x32_bf16(va00, mb0, oacc0, 0, 0, 0);
    oacc0 = __builtin_amdgcn_mfma_f32_16x16x32_bf16(va01, mb1, oacc0, 0, 0, 0);
    oacc1 = __builtin_amdgcn_mfma_f32_16x16x32_bf16(va10, mb0, oacc1, 0, 0, 0);
    oacc1 = __builtin_amdgcn_mfma_f32_16x16x32_bf16(va11, mb1, oacc1, 0, 0, 0);
#pragma unroll
    for (int r = 0; r < 4; ++r) {
      int gn0 = nb0 + r0 + quad * 4 + r;
      int gn1 = gn0 + 16;
      if (gn0 < N) out[(size_t)gn0 * 64 + ot * 16 + l15] = oacc0[r];
      if (gn1 < N) out[(size_t)gn1 * 64 + ot * 16 + l15] = oacc1[r];
    }
  }
}

// ---------------------------------------------------------------------------
extern "C" void kernel_launch(void* const* d_in, const int* in_sizes, int n_in,
                              void* d_out, int out_size, void* d_ws, size_t ws_size,
                              hipStream_t stream) {
  const float* x    = (const float*)d_in[0];
  const float* ea   = (const float*)d_in[1];
  const int*   ei   = (const int*)d_in[2];
  const float* k1W1 = (const float*)d_in[3];
  const float* k1b1 = (const float*)d_in[4];
  const float* k1W2 = (const float*)d_in[5];
  const float* k1b2 = (const float*)d_in[6];
  const float* k2W1 = (const float*)d_in[7];
  const float* k2b1 = (const float*)d_in[8];
  const float* k2W2 = (const float*)d_in[9];
  const float* k2b2 = (const float*)d_in[10];
  const float* mixW = (const float*)d_in[11];
  const float* mixb = (const float*)d_in[12];
  float* out = (float*)d_out;

  const int N = in_sizes[0] / 64;
  const int E = in_sizes[2] / 2;
  const int nbkt = (N + 127) >> 7;

  // ws layout (~30 MB):
  //   kyb bf16 [N*64] | slab u32 [nbkt*CAP] | bcnt [nbkt] | beg[N] | deg[N] |
  //   W2T1b bf16 [65536] | W2T2b bf16 [65536] | mixWb bf16 [4096]
  // vconv (fp32, N*64) lives in d_out (k_out reads own rows before writing).
  unsigned short* kyb = (unsigned short*)d_ws;
  unsigned* slab = (unsigned*)(kyb + (size_t)N * 64);
  int* bcnt = (int*)(slab + (size_t)nbkt * CAP);
  int* beg  = bcnt + nbkt;
  int* deg  = beg + N;
  unsigned short* W2T1b = (unsigned short*)(deg + N);
  unsigned short* W2T2b = W2T1b + 65536;
  unsigned short* mixWb = W2T2b + 65536;
  float* vconv = out;

  const int gblocks = (N + NBG - 1) / NBG;
  const int bblocks = (E + CHUNK - 1) / CHUNK;

  // Phase 0: weight conversions + bcnt zeroing, one dispatch
  k_prep<<<dim3(33), dim3(THREADS), 0, stream>>>(
      k1W2, k2W2, mixW, W2T1b, W2T2b, mixWb, bcnt, nbkt);

  // Phase 1: MLP1 GEMM -> ky bf16
  k_kyv<<<dim3(gblocks), dim3(THREADS), 0, stream>>>(
      x, ea, k1W1, k1b1, W2T1b, k1b2, kyb, N);

  // Phase 2: bin by 128-node bucket, then sort + writeback + beg/deg
  k_bin<<<dim3(bblocks), dim3(THREADS), 0, stream>>>(ei, slab, bcnt, E, N);
  k_csr<<<dim3(nbkt), dim3(THREADS), 0, stream>>>(slab, bcnt, beg, deg, N);

  // Phase 3: gather (high occupancy, pairwise ILP) -> vconv (d_out)
  k_gather<<<dim3((N + 63) / 64), dim3(THREADS), 0, stream>>>(
      slab, beg, deg, kyb, vconv, N);

  // Phase 4: MLP2 GEMM + mix
  k_out<<<dim3(gblocks), dim3(THREADS), 0, stream>>>(
      vconv, ea, k2W1, k2b1, W2T2b, k2b2, mixWb, mixb, out, N);
}